// Round 1
// baseline (9193.880 us; speedup 1.0000x reference)
//
#include <hip/hip_runtime.h>

#define Nn 16384
#define Ee 262144
#define Dd 128
#define DEe 64
#define Hh 256
#define KK 16
#define NSPLIT 8
#define SPS (Nn / NSPLIT) /* sources per split = 2048 */

// edge_index access: mode=1 -> int32 layout, mode=0 -> int64 (low words at even positions)
__device__ __forceinline__ int ld_src(const int* ei, int e, int mode) {
  return mode ? ei[e] : ei[2 * e];
}
__device__ __forceinline__ int ld_dst(const int* ei, int e, int mode) {
  return mode ? ei[Ee + e] : ei[2 * Ee + 2 * e];
}

__global__ void k_detect(const int* __restrict__ ei, int* __restrict__ flag) {
  if (blockIdx.x == 0 && threadIdx.x == 0) {
    int any = 0;
    for (int i = 0; i < 64; ++i) any |= ei[2 * i + 1];
    *flag = (any != 0) ? 1 : 0;  // any odd word nonzero -> int32 layout
  }
}

__global__ void k_hist(const int* __restrict__ ei, const int* __restrict__ mode_p,
                       int* __restrict__ hist) {
  int e = blockIdx.x * 256 + threadIdx.x;
  int mode = *mode_p;
  atomicAdd(&hist[ld_dst(ei, e, mode)], 1);
}

__global__ void k_scan(const int* __restrict__ hist, int* __restrict__ cursor) {
  __shared__ int part[256];
  __shared__ int partx[256];
  int t = threadIdx.x;
  int base = t * (Nn / 256);
  int s = 0;
  for (int i = 0; i < Nn / 256; ++i) s += hist[base + i];
  part[t] = s;
  __syncthreads();
  if (t == 0) {
    int run = 0;
    for (int i = 0; i < 256; ++i) { partx[i] = run; run += part[i]; }
  }
  __syncthreads();
  int run = partx[t];
  for (int i = 0; i < Nn / 256; ++i) { int v = hist[base + i]; cursor[base + i] = run; run += v; }
}

__global__ void k_scatter(const int* __restrict__ ei, const int* __restrict__ mode_p,
                          int* __restrict__ cursor, int* __restrict__ perm,
                          int* __restrict__ dstS) {
  int e = blockIdx.x * 256 + threadIdx.x;
  int mode = *mode_p;
  int d = ld_dst(ei, e, mode);
  int pos = atomicAdd(&cursor[d], 1);
  perm[pos] = e;
  dstS[pos] = d;
}

__global__ void k_sq(const float* __restrict__ x, float* __restrict__ sq) {
  int n = blockIdx.x * 256 + threadIdx.x;
  const float4* p = (const float4*)(x + (size_t)n * Dd);
  float acc = 0.f;
#pragma unroll
  for (int i = 0; i < Dd / 4; ++i) {
    float4 v = p[i];
    acc += v.x * v.x + v.y * v.y + v.z * v.z + v.w * v.w;
  }
  sq[n] = acc;
}

// ---------------- kNN: 64 targets/block, 8-way source split, reg top-16 ----------------
__global__ __launch_bounds__(256, 2) void k_knn_part(const float* __restrict__ x,
                                                     const float* __restrict__ sq,
                                                     float* __restrict__ part_d,
                                                     int* __restrict__ part_i) {
  __shared__ float xtT[128 * 64];  // targets, [k][i]
  __shared__ float smS[128 * 64];  // sources [k][j], aliased as dtile [j][i] pitch 68
  int tid = threadIdx.x;
  int tileT = blockIdx.x >> 3;
  int split = blockIdx.x & 7;
  int tb = tileT * 64;
  int r = tid & 63, q = tid >> 6;
#pragma unroll
  for (int pass = 0; pass < 8; ++pass) {
    int k0 = pass * 16 + q * 4;
    float4 v = *(const float4*)&x[(size_t)(tb + r) * Dd + k0];
    xtT[(k0 + 0) * 64 + r] = v.x;
    xtT[(k0 + 1) * 64 + r] = v.y;
    xtT[(k0 + 2) * 64 + r] = v.z;
    xtT[(k0 + 3) * 64 + r] = v.w;
  }
  float bd[KK];
  int bi[KK];
#pragma unroll
  for (int p2 = 0; p2 < KK; ++p2) { bd[p2] = 3.0e38f; bi[p2] = 0x7fffffff; }
  int rg = tid >> 4, cg = tid & 15;
  for (int t = 0; t < SPS / 64; ++t) {
    int sb = split * SPS + t * 64;
    __syncthreads();  // previous scan done before restaging smS
#pragma unroll
    for (int pass = 0; pass < 8; ++pass) {
      int k0 = pass * 16 + q * 4;
      float4 v = *(const float4*)&x[(size_t)(sb + r) * Dd + k0];
      smS[(k0 + 0) * 64 + r] = v.x;
      smS[(k0 + 1) * 64 + r] = v.y;
      smS[(k0 + 2) * 64 + r] = v.z;
      smS[(k0 + 3) * 64 + r] = v.w;
    }
    __syncthreads();
    float acc[16];
#pragma unroll
    for (int i = 0; i < 16; ++i) acc[i] = 0.f;
#pragma unroll 4
    for (int k = 0; k < Dd; ++k) {
      float4 a = *(const float4*)&xtT[k * 64 + rg * 4];
      float4 b = *(const float4*)&smS[k * 64 + cg * 4];
      acc[0] += a.x * b.x; acc[1] += a.x * b.y; acc[2] += a.x * b.z; acc[3] += a.x * b.w;
      acc[4] += a.y * b.x; acc[5] += a.y * b.y; acc[6] += a.y * b.z; acc[7] += a.y * b.w;
      acc[8] += a.z * b.x; acc[9] += a.z * b.y; acc[10] += a.z * b.z; acc[11] += a.z * b.w;
      acc[12] += a.w * b.x; acc[13] += a.w * b.y; acc[14] += a.w * b.z; acc[15] += a.w * b.w;
    }
    __syncthreads();  // all smS reads done -> safe to alias as dtile
    float sqi0 = sq[tb + rg * 4 + 0];
    float sqi1 = sq[tb + rg * 4 + 1];
    float sqi2 = sq[tb + rg * 4 + 2];
    float sqi3 = sq[tb + rg * 4 + 3];
#pragma unroll
    for (int jj = 0; jj < 4; ++jj) {
      int j = cg * 4 + jj;
      float sqj = sq[sb + j];
      float4 dv;
      dv.x = (sqi0 - 2.f * acc[0 + jj]) + sqj;   // match reference association
      dv.y = (sqi1 - 2.f * acc[4 + jj]) + sqj;
      dv.z = (sqi2 - 2.f * acc[8 + jj]) + sqj;
      dv.w = (sqi3 - 2.f * acc[12 + jj]) + sqj;
      *(float4*)&smS[j * 68 + rg * 4] = dv;  // dtile[j][i]
    }
    __syncthreads();
    if (tid < 64) {
#pragma unroll 1
      for (int j = 0; j < 64; ++j) {
        float d = smS[j * 68 + tid];
        int gidx = sb + j;
        if (d < bd[KK - 1]) {  // strict < : ties keep earlier (lower) index, like jax top_k
#pragma unroll
          for (int p = KK - 1; p >= 1; --p) {
            bool shift = d < bd[p - 1];
            bool here = (!shift) && (d < bd[p]);
            float nb = shift ? bd[p - 1] : (here ? d : bd[p]);
            int ni = shift ? bi[p - 1] : (here ? gidx : bi[p]);
            bd[p] = nb;
            bi[p] = ni;
          }
          if (d < bd[0]) { bd[0] = d; bi[0] = gidx; }
        }
      }
    }
  }
  if (tid < 64) {
    size_t base = ((size_t)(tb + tid) * NSPLIT + split) * KK;
#pragma unroll
    for (int p = 0; p < KK; ++p) {
      part_d[base + p] = bd[p];
      part_i[base + p] = bi[p];
    }
  }
}

__global__ void k_knn_merge(const float* __restrict__ part_d, const int* __restrict__ part_i,
                            int* __restrict__ knn_src) {
  int n = blockIdx.x * 256 + threadIdx.x;
  const float* pd = part_d + (size_t)n * NSPLIT * KK;
  const int* pi = part_i + (size_t)n * NSPLIT * KK;
  int pos[NSPLIT];
#pragma unroll
  for (int l = 0; l < NSPLIT; ++l) pos[l] = 0;
  for (int o = 0; o < KK; ++o) {
    float bestd = 3.3e38f;
    int besti = 0x7fffffff;
    int bestl = 0;
#pragma unroll
    for (int l = 0; l < NSPLIT; ++l) {
      if (pos[l] < KK) {
        float dd = pd[l * KK + pos[l]];
        int ii = pi[l * KK + pos[l]];
        if (dd < bestd || (dd == bestd && ii < besti)) { bestd = dd; besti = ii; bestl = l; }
      }
    }
    knn_src[n * KK + o] = besti;
#pragma unroll
    for (int l = 0; l < NSPLIT; ++l) pos[l] += (l == bestl) ? 1 : 0;
  }
}

// ---------------- fused 2-layer MLP cores (32 rows/block, H=256, out=128) ----------------
// smA: inT [k][32] (k<indim) during L1, then hidden [32 rows][pitch 260] fp32
// smB: weight K-chunk staging (2048 floats)
__device__ __forceinline__ void mlp_l1(int tid, int indim, const float* __restrict__ W1,
                                       const float* __restrict__ b1, float* smA, float* smB) {
  int rg = tid >> 5, cg = tid & 31;  // rows rg*4..+4, cols cg*8..+8
  float acc[32];
#pragma unroll
  for (int i = 0; i < 32; ++i) acc[i] = 0.f;
  for (int kc = 0; kc < indim / 8; ++kc) {
    const float* W1g = W1 + (size_t)kc * 8 * Hh;
    *(float4*)&smB[tid * 4] = *(const float4*)&W1g[tid * 4];
    *(float4*)&smB[1024 + tid * 4] = *(const float4*)&W1g[1024 + tid * 4];
    __syncthreads();
#pragma unroll
    for (int k = 0; k < 8; ++k) {
      int kk = kc * 8 + k;
      float4 a0 = *(const float4*)&smA[kk * 32 + rg * 4];
      float4 b0 = *(const float4*)&smB[k * Hh + cg * 8];
      float4 b1v = *(const float4*)&smB[k * Hh + cg * 8 + 4];
      float av[4] = {a0.x, a0.y, a0.z, a0.w};
      float bv[8] = {b0.x, b0.y, b0.z, b0.w, b1v.x, b1v.y, b1v.z, b1v.w};
#pragma unroll
      for (int rr = 0; rr < 4; ++rr)
#pragma unroll
        for (int cc = 0; cc < 8; ++cc) acc[rr * 8 + cc] += av[rr] * bv[cc];
    }
    __syncthreads();
  }
  float4 bb0 = *(const float4*)&b1[cg * 8];
  float4 bb1 = *(const float4*)&b1[cg * 8 + 4];
  float bs[8] = {bb0.x, bb0.y, bb0.z, bb0.w, bb1.x, bb1.y, bb1.z, bb1.w};
#pragma unroll
  for (int rr = 0; rr < 4; ++rr) {
    int row = rg * 4 + rr;
    float4 h0, h1;
    h0.x = fmaxf(acc[rr * 8 + 0] + bs[0], 0.f);
    h0.y = fmaxf(acc[rr * 8 + 1] + bs[1], 0.f);
    h0.z = fmaxf(acc[rr * 8 + 2] + bs[2], 0.f);
    h0.w = fmaxf(acc[rr * 8 + 3] + bs[3], 0.f);
    h1.x = fmaxf(acc[rr * 8 + 4] + bs[4], 0.f);
    h1.y = fmaxf(acc[rr * 8 + 5] + bs[5], 0.f);
    h1.z = fmaxf(acc[rr * 8 + 6] + bs[6], 0.f);
    h1.w = fmaxf(acc[rr * 8 + 7] + bs[7], 0.f);
    *(float4*)&smA[row * 260 + cg * 8] = h0;
    *(float4*)&smA[row * 260 + cg * 8 + 4] = h1;
  }
  __syncthreads();
}

__device__ __forceinline__ void mlp_l2(int tid, const float* __restrict__ W2,
                                       const float* smA, float* smB, float acc2[16]) {
  int rg2 = tid >> 5, cg2 = tid & 31;  // rows rg2*4..+4, cols cg2*4..+4
#pragma unroll
  for (int i = 0; i < 16; ++i) acc2[i] = 0.f;
  for (int kc = 0; kc < Hh / 16; ++kc) {
    const float* W2g = W2 + (size_t)kc * 16 * Dd;
    *(float4*)&smB[tid * 4] = *(const float4*)&W2g[tid * 4];
    *(float4*)&smB[1024 + tid * 4] = *(const float4*)&W2g[1024 + tid * 4];
    __syncthreads();
#pragma unroll
    for (int k = 0; k < 16; ++k) {
      int kk = kc * 16 + k;
      float4 b0 = *(const float4*)&smB[k * Dd + cg2 * 4];
#pragma unroll
      for (int rr = 0; rr < 4; ++rr) {
        float a = smA[(rg2 * 4 + rr) * 260 + kk];
        acc2[rr * 4 + 0] += a * b0.x;
        acc2[rr * 4 + 1] += a * b0.y;
        acc2[rr * 4 + 2] += a * b0.z;
        acc2[rr * 4 + 3] += a * b0.w;
      }
    }
    __syncthreads();
  }
}

// ---------------- static message MLP + grouped scatter-add ----------------
__global__ __launch_bounds__(256, 3) void k_static_msg(
    const float* __restrict__ xs, const float* __restrict__ ea, const int* __restrict__ ei,
    const int* __restrict__ mode_p, const int* __restrict__ perm, const int* __restrict__ dstS,
    const float* __restrict__ W1, const float* __restrict__ b1, const float* __restrict__ W2,
    const float* __restrict__ b2, float* __restrict__ agg) {
  __shared__ float smA[32 * 260];
  __shared__ float smB[2048];
  __shared__ int dstLoc[32];
  int tid = threadIdx.x;
  int pb = blockIdx.x * 32;
  int mode = *mode_p;
  int r = tid & 31, q = tid >> 5;
  int p = pb + r;
  int e = perm[p];
  int ds = dstS[p];
  int sr = ld_src(ei, e, mode);
  if (q == 0) dstLoc[r] = ds;
  const float* eap = ea + (size_t)e * DEe;
#pragma unroll
  for (int m = 0; m < 2; ++m) {
    int k0 = q * 8 + m * 4;
    float4 v = *(const float4*)&eap[k0];
    smA[(k0 + 0) * 32 + r] = v.x;
    smA[(k0 + 1) * 32 + r] = v.y;
    smA[(k0 + 2) * 32 + r] = v.z;
    smA[(k0 + 3) * 32 + r] = v.w;
  }
  const float* xsp = xs + (size_t)sr * Dd;
  const float* xdp = xs + (size_t)ds * Dd;
#pragma unroll
  for (int m = 0; m < 4; ++m) {
    int f0 = q * 16 + m * 4;
    float4 a = *(const float4*)&xsp[f0];
    float4 b = *(const float4*)&xdp[f0];
    smA[(DEe + f0 + 0) * 32 + r] = a.x - b.x;
    smA[(DEe + f0 + 1) * 32 + r] = a.y - b.y;
    smA[(DEe + f0 + 2) * 32 + r] = a.z - b.z;
    smA[(DEe + f0 + 3) * 32 + r] = a.w - b.w;
  }
  __syncthreads();
  mlp_l1(tid, DEe + Dd, W1, b1, smA, smB);
  float acc2[16];
  mlp_l2(tid, W2, smA, smB, acc2);
  int rg2 = tid >> 5, cg2 = tid & 31;
  float4 ob = *(const float4*)&b2[cg2 * 4];
#pragma unroll
  for (int rr = 0; rr < 4; ++rr) {
    int row = rg2 * 4 + rr;
    float4 o;
    o.x = fmaxf(acc2[rr * 4 + 0] + ob.x, 0.f);
    o.y = fmaxf(acc2[rr * 4 + 1] + ob.y, 0.f);
    o.z = fmaxf(acc2[rr * 4 + 2] + ob.z, 0.f);
    o.w = fmaxf(acc2[rr * 4 + 3] + ob.w, 0.f);
    *(float4*)&smA[row * 132 + cg2 * 4] = o;  // outT [32][132]
  }
  __syncthreads();
  int col = tid & 127, half = tid >> 7;
  int r0 = half * 16;
  float run = smA[r0 * 132 + col];
  int prevd = dstLoc[r0];
  for (int rr = 1; rr < 16; ++rr) {
    int row = r0 + rr;
    int dd2 = dstLoc[row];
    float v = smA[row * 132 + col];
    if (dd2 != prevd) {
      atomicAdd(&agg[(size_t)prevd * Dd + col], run);
      run = v;
      prevd = dd2;
    } else {
      run += v;
    }
  }
  atomicAdd(&agg[(size_t)prevd * Dd + col], run);
}

// ---------------- dynamic (kNN) message MLP, atomic-free aggregation ----------------
__global__ __launch_bounds__(256, 3) void k_dyn_msg(
    const float* __restrict__ xd, const int* __restrict__ knn, const float* __restrict__ W1,
    const float* __restrict__ b1, const float* __restrict__ W2, const float* __restrict__ b2,
    float* __restrict__ agg) {
  __shared__ float smA[32 * 260];
  __shared__ float smB[2048];
  __shared__ float pbuf[4 * 128];
  int tid = threadIdx.x;
  int nb2 = blockIdx.x * 2;  // 2 targets, 16 messages each = 32 rows
  int r = tid & 31, q = tid >> 5;
  int tgt = nb2 + (r >> 4);
  int nj = knn[tgt * KK + (r & 15)];
  const float* xip = xd + (size_t)tgt * Dd;
  const float* xjp = xd + (size_t)nj * Dd;
#pragma unroll
  for (int m = 0; m < 4; ++m) {
    int f0 = q * 16 + m * 4;
    float4 v = *(const float4*)&xip[f0];
    float4 a = *(const float4*)&xjp[f0];
    smA[(f0 + 0) * 32 + r] = v.x;
    smA[(f0 + 1) * 32 + r] = v.y;
    smA[(f0 + 2) * 32 + r] = v.z;
    smA[(f0 + 3) * 32 + r] = v.w;
    smA[(Dd + f0 + 0) * 32 + r] = a.x - v.x;
    smA[(Dd + f0 + 1) * 32 + r] = a.y - v.y;
    smA[(Dd + f0 + 2) * 32 + r] = a.z - v.z;
    smA[(Dd + f0 + 3) * 32 + r] = a.w - v.w;
  }
  __syncthreads();
  mlp_l1(tid, 2 * Dd, W1, b1, smA, smB);
  float acc2[16];
  mlp_l2(tid, W2, smA, smB, acc2);
  int rg2 = tid >> 5, cg2 = tid & 31;
  float4 ob = *(const float4*)&b2[cg2 * 4];
  float s0 = 0.f, s1 = 0.f, s2 = 0.f, s3 = 0.f;
#pragma unroll
  for (int rr = 0; rr < 4; ++rr) {
    s0 += fmaxf(acc2[rr * 4 + 0] + ob.x, 0.f);
    s1 += fmaxf(acc2[rr * 4 + 1] + ob.y, 0.f);
    s2 += fmaxf(acc2[rr * 4 + 2] + ob.z, 0.f);
    s3 += fmaxf(acc2[rr * 4 + 3] + ob.w, 0.f);
  }
  s0 += __shfl_xor(s0, 32);
  s1 += __shfl_xor(s1, 32);
  s2 += __shfl_xor(s2, 32);
  s3 += __shfl_xor(s3, 32);
  if ((rg2 & 1) == 0) {
    float4 o;
    o.x = s0; o.y = s1; o.z = s2; o.w = s3;
    *(float4*)&pbuf[(rg2 >> 1) * 128 + cg2 * 4] = o;
  }
  __syncthreads();
  int c = tid & 127, g = tid >> 7;
  float v = pbuf[(g * 2) * 128 + c] + pbuf[(g * 2 + 1) * 128 + c];
  agg[(size_t)(nb2 + g) * Dd + c] = v;
}

// ---------------- generic node MLP (update / fuse) ----------------
__global__ __launch_bounds__(256, 3) void k_node_mlp2(
    const float* __restrict__ in1, const float* __restrict__ in2, int indim,
    const float* __restrict__ W1, const float* __restrict__ b1, const float* __restrict__ W2,
    const float* __restrict__ b2, float* __restrict__ out) {
  __shared__ float smA[32 * 260];
  __shared__ float smB[2048];
  int tid = threadIdx.x;
  int nb = blockIdx.x * 32;
  int r = tid & 31, q = tid >> 5;
  for (int pass = 0; pass < indim / 32; ++pass) {
    int k0 = pass * 32 + q * 4;
    float4 v;
    if (k0 < Dd)
      v = *(const float4*)&in1[(size_t)(nb + r) * Dd + k0];
    else
      v = *(const float4*)&in2[(size_t)(nb + r) * Dd + (k0 - Dd)];
    smA[(k0 + 0) * 32 + r] = v.x;
    smA[(k0 + 1) * 32 + r] = v.y;
    smA[(k0 + 2) * 32 + r] = v.z;
    smA[(k0 + 3) * 32 + r] = v.w;
  }
  __syncthreads();
  mlp_l1(tid, indim, W1, b1, smA, smB);
  float acc2[16];
  mlp_l2(tid, W2, smA, smB, acc2);
  int rg2 = tid >> 5, cg2 = tid & 31;
  float4 ob = *(const float4*)&b2[cg2 * 4];
#pragma unroll
  for (int rr = 0; rr < 4; ++rr) {
    float4 o;
    o.x = fmaxf(acc2[rr * 4 + 0] + ob.x, 0.f);
    o.y = fmaxf(acc2[rr * 4 + 1] + ob.y, 0.f);
    o.z = fmaxf(acc2[rr * 4 + 2] + ob.z, 0.f);
    o.w = fmaxf(acc2[rr * 4 + 3] + ob.w, 0.f);
    *(float4*)&out[(size_t)(nb + rg2 * 4 + rr) * Dd + cg2 * 4] = o;
  }
}

// ---------------- edge refiner: ea = relu(ea @ rW + rb), 64->64 ----------------
__global__ __launch_bounds__(256) void k_refine(const float* __restrict__ ein,
                                                const float* __restrict__ rW,
                                                const float* __restrict__ rb,
                                                float* __restrict__ eout) {
  __shared__ float lea[16 * 64];
  __shared__ float ldsW[64 * 64];
  int tid = threadIdx.x;
  int eb = blockIdx.x * 16;
  *(float4*)&lea[tid * 4] = *(const float4*)&ein[(size_t)eb * DEe + tid * 4];
#pragma unroll
  for (int m = 0; m < 4; ++m) {
    int i4 = tid + m * 256;
    *(float4*)&ldsW[i4 * 4] = *(const float4*)&rW[i4 * 4];
  }
  __syncthreads();
  int j = tid & 63, eg = tid >> 6;  // thread: output col j for edges eg, eg+4, eg+8, eg+12
  float bias = rb[j];
  float acc0 = 0.f, acc1 = 0.f, acc2 = 0.f, acc3 = 0.f;
#pragma unroll 8
  for (int k = 0; k < 64; ++k) {
    float w = ldsW[k * 64 + j];
    acc0 += lea[(eg + 0) * 64 + k] * w;
    acc1 += lea[(eg + 4) * 64 + k] * w;
    acc2 += lea[(eg + 8) * 64 + k] * w;
    acc3 += lea[(eg + 12) * 64 + k] * w;
  }
  eout[(size_t)(eb + eg + 0) * DEe + j] = fmaxf(acc0 + bias, 0.f);
  eout[(size_t)(eb + eg + 4) * DEe + j] = fmaxf(acc1 + bias, 0.f);
  eout[(size_t)(eb + eg + 8) * DEe + j] = fmaxf(acc2 + bias, 0.f);
  eout[(size_t)(eb + eg + 12) * DEe + j] = fmaxf(acc3 + bias, 0.f);
}

extern "C" void kernel_launch(void* const* d_in, const int* in_sizes, int n_in, void* d_out,
                              int out_size, void* d_ws, size_t ws_size, hipStream_t stream) {
  (void)in_sizes; (void)n_in; (void)out_size; (void)ws_size;
  const float* x = (const float*)d_in[0];
  const float* edge_attr = (const float*)d_in[1];
  const float* sW1 = (const float*)d_in[2];
  const float* sb1 = (const float*)d_in[3];
  const float* sW2 = (const float*)d_in[4];
  const float* sb2 = (const float*)d_in[5];
  const float* uW1 = (const float*)d_in[6];
  const float* ub1 = (const float*)d_in[7];
  const float* uW2 = (const float*)d_in[8];
  const float* ub2 = (const float*)d_in[9];
  const float* rW = (const float*)d_in[10];
  const float* rb = (const float*)d_in[11];
  const float* dW1 = (const float*)d_in[12];
  const float* db1 = (const float*)d_in[13];
  const float* dW2 = (const float*)d_in[14];
  const float* db2 = (const float*)d_in[15];
  const float* dUW1 = (const float*)d_in[16];
  const float* dUb1 = (const float*)d_in[17];
  const float* dUW2 = (const float*)d_in[18];
  const float* dUb2 = (const float*)d_in[19];
  const float* fW1 = (const float*)d_in[20];
  const float* fb1 = (const float*)d_in[21];
  const float* fW2 = (const float*)d_in[22];
  const float* fb2 = (const float*)d_in[23];
  const int* ei = (const int*)d_in[24];
  float* out = (float*)d_out;

  float* wsf = (float*)d_ws;
  size_t off = 0;
  float* ea_ws = wsf + off; off += (size_t)Ee * DEe;
  float* xs_ws = wsf + off; off += (size_t)Nn * Dd;
  float* xd_ws = wsf + off; off += (size_t)Nn * Dd;
  float* agg = wsf + off;   off += (size_t)Nn * Dd;
  float* sq = wsf + off;    off += Nn;
  float* part_d = wsf + off; off += (size_t)Nn * NSPLIT * KK;
  int* part_i = (int*)(wsf + off); off += (size_t)Nn * NSPLIT * KK;
  int* knn_src = (int*)(wsf + off); off += (size_t)Nn * KK;
  int* hist = (int*)(wsf + off);   off += Nn;
  int* cursor = (int*)(wsf + off); off += Nn;
  int* perm = (int*)(wsf + off);   off += Ee;
  int* dstS = (int*)(wsf + off);   off += Ee;
  int* modep = (int*)(wsf + off);  off += 1;

  // edge_index layout probe + counting sort by dst (CSR ordering)
  k_detect<<<1, 64, 0, stream>>>(ei, modep);
  hipMemsetAsync(hist, 0, Nn * sizeof(int), stream);
  k_hist<<<Ee / 256, 256, 0, stream>>>(ei, modep, hist);
  k_scan<<<1, 256, 0, stream>>>(hist, cursor);
  k_scatter<<<Ee / 256, 256, 0, stream>>>(ei, modep, cursor, perm, dstS);

  // ---- static branch: 3 convs + 2 refiners ----
  const float* xs_cur = x;
  const float* ea_cur = edge_attr;
  for (int i = 0; i < 3; ++i) {
    hipMemsetAsync(agg, 0, (size_t)Nn * Dd * sizeof(float), stream);
    k_static_msg<<<Ee / 32, 256, 0, stream>>>(
        xs_cur, ea_cur, ei, modep, perm, dstS, sW1 + (size_t)i * (DEe + Dd) * Hh,
        sb1 + (size_t)i * Hh, sW2 + (size_t)i * Hh * Dd, sb2 + (size_t)i * Dd, agg);
    k_node_mlp2<<<Nn / 32, 256, 0, stream>>>(
        agg, (const float*)nullptr, Dd, uW1 + (size_t)i * Dd * Hh, ub1 + (size_t)i * Hh,
        uW2 + (size_t)i * Hh * Dd, ub2 + (size_t)i * Dd, xs_ws);
    xs_cur = xs_ws;
    if (i < 2) {
      k_refine<<<Ee / 16, 256, 0, stream>>>(ea_cur, rW + (size_t)i * DEe * DEe,
                                            rb + (size_t)i * DEe, ea_ws);
      ea_cur = ea_ws;
    }
  }

  // ---- dynamic branch: 2 kNN convs ----
  const float* xd_cur = x;
  for (int i = 0; i < 2; ++i) {
    k_sq<<<Nn / 256, 256, 0, stream>>>(xd_cur, sq);
    k_knn_part<<<(Nn / 64) * NSPLIT, 256, 0, stream>>>(xd_cur, sq, part_d, part_i);
    k_knn_merge<<<Nn / 256, 256, 0, stream>>>(part_d, part_i, knn_src);
    k_dyn_msg<<<Nn / 2, 256, 0, stream>>>(
        xd_cur, knn_src, dW1 + (size_t)i * 2 * Dd * Hh, db1 + (size_t)i * Hh,
        dW2 + (size_t)i * Hh * Dd, db2 + (size_t)i * Dd, agg);
    k_node_mlp2<<<Nn / 32, 256, 0, stream>>>(
        agg, (const float*)nullptr, Dd, dUW1 + (size_t)i * Dd * Hh, dUb1 + (size_t)i * Hh,
        dUW2 + (size_t)i * Hh * Dd, dUb2 + (size_t)i * Dd, xd_ws);
    xd_cur = xd_ws;
  }

  // ---- fuse MLP: concat(xs, xd) 256 -> 256 -> 128 ----
  k_node_mlp2<<<Nn / 32, 256, 0, stream>>>(xs_ws, xd_ws, 2 * Dd, fW1, fb1, fW2, fb2, out);
}